// Round 16
// baseline (1070.690 us; speedup 1.0000x reference)
//
#include <hip/hip_runtime.h>
#include <hip/hip_fp16.h>

#define NB   256
#define TT   1024
#define II   64
#define NT   768

typedef _Float16 f16;
typedef _Float16 f16x4 __attribute__((ext_vector_type(4)));
typedef _Float16 hf8 __attribute__((ext_vector_type(8)));
typedef float    ff4 __attribute__((ext_vector_type(4)));

__device__ __forceinline__ float rcp_fast(float x){
    float r; asm("v_rcp_f32 %0, %1" : "=v"(r) : "v"(x)); return r;
}
__device__ __forceinline__ float exp2_fast(float x){
    float r; asm("v_exp_f32 %0, %1" : "=v"(r) : "v"(x)); return r;
}
__device__ __forceinline__ float sigm(float x){
    return rcp_fast(1.0f + exp2_fast(x * -1.44269504f));
}
__device__ __forceinline__ float tanh_f(float x){
    return fmaf(-2.0f, rcp_fast(1.0f + exp2_fast(x * 2.88539008f)), 1.0f);
}
__device__ __forceinline__ hf8 cvt8(float4 a, float4 b){
    hf8 r;
    r[0]=(f16)a.x; r[1]=(f16)a.y; r[2]=(f16)a.z; r[3]=(f16)a.w;
    r[4]=(f16)b.x; r[5]=(f16)b.y; r[6]=(f16)b.z; r[7]=(f16)b.w;
    return r;
}
__device__ __forceinline__ hf8 ldw8(const float* src){
    float4 v0 = *(const float4*)src;
    float4 v1 = *(const float4*)(src + 4);
    return cvt8(v0, v1);
}

// R16 = R15 structure at 12 waves (3/SIMD) for phase overlap.
// Gate-interleaved tiles (verified R5-R15): gate-row R = (rho&3)*H + 4*tau
// + (rho>>2); C/D row = kg*4+reg => lane (kg,rho) holds gates i,f,g,o of
// unit 4*tau+kg in acc[i]; active lanes rho<4 select tile i=rho (2-level
// cndmask tree), unit = 16*wv + 4*rho + kg.
// Waves 0-7: L1, 4 tiles x 4 h-kt (16 MFMA/step) + GEMM 4 x-tiles x 2 kt
//            (burst at t%16==15) + xg scatter-read consume.
// Waves 8-11: L2, 4 tiles x 6 kt (24 MFMA/step), setprio(1) cluster (T5).
// Per SIMD: {L1, L1, L2} -> 56 MFMA/step + role diversity for overlap.
// xg[2][16][520] f16 dbuf; x loaded at t%16==14, cvt to f16 same step
// (only 8 regs cross into the burst step).

__launch_bounds__(NT, 3)
__global__ void lstm_mfma(const float* __restrict__ x,
                          const float* __restrict__ Wih1, const float* __restrict__ Whh1,
                          const float* __restrict__ bih1, const float* __restrict__ bhh1,
                          const float* __restrict__ Wih2, const float* __restrict__ Whh2,
                          const float* __restrict__ bih2, const float* __restrict__ bhh2,
                          const float* __restrict__ W1,   const float* __restrict__ b1,
                          const float* __restrict__ W2,   const float* __restrict__ b2,
                          float* __restrict__ out)
{
    __shared__ __align__(16) f16 xg[2][16][520];   // 33 KB, row pad 520
    __shared__ __align__(16) f16 h1buf[2][128];
    __shared__ __align__(16) f16 h2buf[2][64];
    __shared__ float headbuf[32];

    const int j    = threadIdx.x;      // 0..767
    const int b    = blockIdx.x;
    const int wave = j >> 6;           // 0..11
    const int lane = j & 63;
    const int rho  = lane & 15;
    const int kg   = lane >> 4;        // 0..3
    const bool l2w = (wave >= 8);
    const int  wv  = l2w ? (wave - 8) : wave;

    const float* xb = x + (size_t)b * TT * II;

    // chunk-0 x loads first (L1 waves; latency covered by weight loading)
    float4 xl0, xl1, xl2, xl3;
    if (!l2w){
        const float* xp = xb + (size_t)rho * II + kg*8;
        xl0 = *(const float4*)xp;       xl1 = *(const float4*)(xp + 4);
        xl2 = *(const float4*)(xp + 32);xl3 = *(const float4*)(xp + 36);
    }

    // ---------- weights ----------
    hf8 A[24];                          // L1: A[i*4+kt] i<4 | L2: A[i*6+kt] i<4
    hf8 AX[8];                          // L1 only: GEMM tiles
    ff4 biasX[4];
    float b2l0 = 0.f, b2l1 = 0.f, b2l2 = 0.f, b2l3 = 0.f;
    if (!l2w){
        #pragma unroll
        for (int i = 0; i < 4; ++i){
            const int tau = 4*wv + i;
            const int R   = (rho & 3)*128 + 4*tau + (rho >> 2);
            #pragma unroll
            for (int kt = 0; kt < 4; ++kt)
                A[i*4 + kt] = ldw8(Whh1 + R*128 + 32*kt + kg*8);
            AX[i*2 + 0] = ldw8(Wih1 + R*64 + kg*8);
            AX[i*2 + 1] = ldw8(Wih1 + R*64 + 32 + kg*8);
            #pragma unroll
            for (int r = 0; r < 4; ++r){
                const int Rb = r*128 + 4*tau + kg;
                biasX[i][r] = bih1[Rb] + bhh1[Rb];
            }
        }
    } else {
        #pragma unroll
        for (int i = 0; i < 4; ++i){
            const int tau2 = 4*wv + i;
            const int R    = (rho & 3)*64 + 4*tau2 + (rho >> 2);
            #pragma unroll
            for (int kt = 0; kt < 6; ++kt)
                A[i*6 + kt] = ldw8((kt < 4) ? (Wih2 + R*128 + 32*kt + kg*8)
                                            : (Whh2 + R*64  + 32*(kt-4) + kg*8));
        }
        const int u2 = 4*(4*wv + (rho & 3)) + kg;   // own unit (clamped dup)
        b2l0 = bih2[u2]       + bhh2[u2];
        b2l1 = bih2[64 + u2]  + bhh2[64 + u2];
        b2l2 = bih2[128 + u2] + bhh2[128 + u2];
        b2l3 = bih2[192 + u2] + bhh2[192 + u2];
    }

    if (j < 128) h1buf[0][j] = (f16)0.0f;
    if (j < 64)  h2buf[0][j] = (f16)0.0f;

    // ---------- prologue GEMM: xg chunk 0 (steps 0..15, L1 waves) ----------
    hf8 xh0, xh1;
    if (!l2w){
        xh0 = cvt8(xl0, xl1);
        xh1 = cvt8(xl2, xl3);
        #pragma unroll
        for (int i = 0; i < 4; ++i){
            ff4 g = __builtin_amdgcn_mfma_f32_16x16x32_f16(AX[i*2+0], xh0, biasX[i], 0, 0, 0);
            g     = __builtin_amdgcn_mfma_f32_16x16x32_f16(AX[i*2+1], xh1, g,        0, 0, 0);
            const int uX = 4*(4*wv + i) + kg;
            f16x4 w; w[0]=(f16)g[0]; w[1]=(f16)g[1]; w[2]=(f16)g[2]; w[3]=(f16)g[3];
            *(f16x4*)&xg[0][rho][uX*4] = w;
        }
    }
    __syncthreads();

    const ff4 zz = {0.0f, 0.0f, 0.0f, 0.0f};
    float c = 0.0f;
    int cur = 0;
    for (int t = 0; t < TT; ++t){
        const int trow = t & 15;
        const int cb   = (t >> 4) & 1;

        // L1: issue next chunk's x loads at t%16==14 (converted same step)
        const bool ldx = (!l2w) && (trow == 14) && (t + 2 < TT);
        if (ldx){
            const float* xp = xb + (size_t)(t + 2 + rho) * II + kg*8;
            xl0 = *(const float4*)xp;       xl1 = *(const float4*)(xp + 4);
            xl2 = *(const float4*)(xp + 32);xl3 = *(const float4*)(xp + 36);
        }

        ff4 qd;
        if (!l2w){
            // xg scatter read hoisted (broadcast within dup lanes)
            const int myUm = 4*(4*wv + (rho & 3)) + kg;
            f16x4 xv = *(const f16x4*)&xg[cb][trow][myUm*4];

            const f16* h1c = h1buf[cur];
            hf8 bf0 = *(const hf8*)(h1c      + kg*8);
            hf8 bf1 = *(const hf8*)(h1c + 32 + kg*8);
            hf8 bf2 = *(const hf8*)(h1c + 64 + kg*8);
            hf8 bf3 = *(const hf8*)(h1c + 96 + kg*8);

            ff4 acc[4];
            #pragma unroll
            for (int i = 0; i < 4; ++i)
                acc[i] = __builtin_amdgcn_mfma_f32_16x16x32_f16(A[i*4+0], bf0, zz, 0, 0, 0);
            #pragma unroll
            for (int i = 0; i < 4; ++i)
                acc[i] = __builtin_amdgcn_mfma_f32_16x16x32_f16(A[i*4+1], bf1, acc[i], 0, 0, 0);
            #pragma unroll
            for (int i = 0; i < 4; ++i)
                acc[i] = __builtin_amdgcn_mfma_f32_16x16x32_f16(A[i*4+2], bf2, acc[i], 0, 0, 0);
            #pragma unroll
            for (int i = 0; i < 4; ++i)
                acc[i] = __builtin_amdgcn_mfma_f32_16x16x32_f16(A[i*4+3], bf3, acc[i], 0, 0, 0);

            ff4 s0 = (rho & 1) ? acc[1] : acc[0];
            ff4 s1 = (rho & 1) ? acc[3] : acc[2];
            qd     = (rho & 2) ? s1 : s0;

            // GEMM burst for next chunk (t%16==15)
            if (trow == 15 && t + 1 < TT){
                #pragma unroll
                for (int i = 0; i < 4; ++i){
                    ff4 g = __builtin_amdgcn_mfma_f32_16x16x32_f16(AX[i*2+0], xh0, biasX[i], 0, 0, 0);
                    g     = __builtin_amdgcn_mfma_f32_16x16x32_f16(AX[i*2+1], xh1, g,        0, 0, 0);
                    const int uX = 4*(4*wv + i) + kg;
                    f16x4 w; w[0]=(f16)g[0]; w[1]=(f16)g[1]; w[2]=(f16)g[2]; w[3]=(f16)g[3];
                    *(f16x4*)&xg[cb ^ 1][rho][uX*4] = w;
                }
            }

            // activation
            float ig = sigm(qd[0] + (float)xv[0]);
            float fg = sigm(qd[1] + (float)xv[1]);
            float gg = tanh_f(qd[2] + (float)xv[2]);
            float og = sigm(qd[3] + (float)xv[3]);
            c = fg*c + ig*gg;
            float hv = og * tanh_f(c);
            if (rho < 4) h1buf[cur ^ 1][4*(4*wv + rho) + kg] = (f16)hv;

            if (ldx){ xh0 = cvt8(xl0, xl1); xh1 = cvt8(xl2, xl3); }
        } else {
            const f16* h1c = h1buf[cur];
            const f16* h2c = h2buf[cur];
            hf8 bf0 = *(const hf8*)(h1c      + kg*8);
            hf8 bf1 = *(const hf8*)(h1c + 32 + kg*8);
            hf8 bf2 = *(const hf8*)(h1c + 64 + kg*8);
            hf8 bf3 = *(const hf8*)(h1c + 96 + kg*8);
            hf8 bf4 = *(const hf8*)(h2c      + kg*8);
            hf8 bf5 = *(const hf8*)(h2c + 32 + kg*8);
            ff4 acc[4];
            __builtin_amdgcn_s_setprio(1);     // T5: L2 staggers vs L1
            #pragma unroll
            for (int i = 0; i < 4; ++i)
                acc[i] = __builtin_amdgcn_mfma_f32_16x16x32_f16(A[i*6+0], bf0, zz, 0, 0, 0);
            #pragma unroll
            for (int kt = 1; kt < 6; ++kt){
                hf8 bb = (kt==1)?bf1:(kt==2)?bf2:(kt==3)?bf3:(kt==4)?bf4:bf5;
                #pragma unroll
                for (int i = 0; i < 4; ++i)
                    acc[i] = __builtin_amdgcn_mfma_f32_16x16x32_f16(A[i*6+kt], bb, acc[i], 0, 0, 0);
            }
            __builtin_amdgcn_s_setprio(0);
            ff4 s0 = (rho & 1) ? acc[1] : acc[0];
            ff4 s1 = (rho & 1) ? acc[3] : acc[2];
            qd     = (rho & 2) ? s1 : s0;

            float hv;
            if (t > 0){
                float ig = sigm(qd[0] + b2l0);
                float fg = sigm(qd[1] + b2l1);
                float gg = tanh_f(qd[2] + b2l2);
                float og = sigm(qd[3] + b2l3);
                c = fg*c + ig*gg;
                hv = og * tanh_f(c);
            } else {
                hv = 0.0f;                 // h2_{-1}=0, c2 untouched
            }
            if (rho < 4) h2buf[cur ^ 1][4*(4*wv + rho) + kg] = (f16)hv;
        }
        __syncthreads();
        cur ^= 1;
    }
    // after loop: cur==0; h1buf[0]=h1_{TT-1}, h2buf[0]=h2_{TT-2}

    // ---- epilogue: L2 step TT-1 (waves 8-11) ----
    if (l2w){
        const f16* h1c = h1buf[0];
        const f16* h2c = h2buf[0];
        hf8 bf0 = *(const hf8*)(h1c      + kg*8);
        hf8 bf1 = *(const hf8*)(h1c + 32 + kg*8);
        hf8 bf2 = *(const hf8*)(h1c + 64 + kg*8);
        hf8 bf3 = *(const hf8*)(h1c + 96 + kg*8);
        hf8 bf4 = *(const hf8*)(h2c      + kg*8);
        hf8 bf5 = *(const hf8*)(h2c + 32 + kg*8);
        ff4 acc[4];
        const ff4 zz2 = {0.0f, 0.0f, 0.0f, 0.0f};
        #pragma unroll
        for (int i = 0; i < 4; ++i)
            acc[i] = __builtin_amdgcn_mfma_f32_16x16x32_f16(A[i*6+0], bf0, zz2, 0, 0, 0);
        #pragma unroll
        for (int kt = 1; kt < 6; ++kt){
            hf8 bb = (kt==1)?bf1:(kt==2)?bf2:(kt==3)?bf3:(kt==4)?bf4:bf5;
            #pragma unroll
            for (int i = 0; i < 4; ++i)
                acc[i] = __builtin_amdgcn_mfma_f32_16x16x32_f16(A[i*6+kt], bb, acc[i], 0, 0, 0);
        }
        ff4 s0 = (rho & 1) ? acc[1] : acc[0];
        ff4 s1 = (rho & 1) ? acc[3] : acc[2];
        ff4 qd = (rho & 2) ? s1 : s0;
        float ig = sigm(qd[0] + b2l0);
        float fg = sigm(qd[1] + b2l1);
        float gg = tanh_f(qd[2] + b2l2);
        float og = sigm(qd[3] + b2l3);
        c = fg*c + ig*gg;
        float hv = og * tanh_f(c);
        if (rho < 4) h2buf[1][4*(4*wv + rho) + kg] = (f16)hv;
    }
    __syncthreads();

    // ---- MLP head (final h2 in h2buf[1]) ----
    if (j < 32){
        float a = b1[j];
        const float* w = W1 + j*64;
        #pragma unroll
        for (int k = 0; k < 64; ++k) a = fmaf(w[k], (float)h2buf[1][k], a);
        headbuf[j] = sigm(a);
    }
    __syncthreads();
    if (j == 0){
        float a = b2[0];
        #pragma unroll
        for (int k = 0; k < 32; ++k) a = fmaf(W2[k], headbuf[k], a);
        out[b] = sigm(a);
    }
}

extern "C" void kernel_launch(void* const* d_in, const int* in_sizes, int n_in,
                              void* d_out, int out_size, void* d_ws, size_t ws_size,
                              hipStream_t stream)
{
    (void)in_sizes; (void)n_in; (void)d_ws; (void)ws_size; (void)out_size;
    lstm_mfma<<<NB, NT, 0, stream>>>(
        (const float*)d_in[0],
        (const float*)d_in[1], (const float*)d_in[2],
        (const float*)d_in[3], (const float*)d_in[4],
        (const float*)d_in[5], (const float*)d_in[6],
        (const float*)d_in[7], (const float*)d_in[8],
        (const float*)d_in[9], (const float*)d_in[10],
        (const float*)d_in[11], (const float*)d_in[12],
        (float*)d_out);
}

// Round 17
// 874.944 us; speedup vs baseline: 1.2237x; 1.2237x over previous
//
#include <hip/hip_runtime.h>
#include <hip/hip_fp16.h>

#define NB   256
#define TT   1024
#define II   64
#define NT   768

typedef _Float16 f16;
typedef _Float16 f16x2 __attribute__((ext_vector_type(2)));
typedef _Float16 f16x4 __attribute__((ext_vector_type(4)));
typedef _Float16 hf8 __attribute__((ext_vector_type(8)));
typedef float    ff4 __attribute__((ext_vector_type(4)));

__device__ __forceinline__ float rcp_fast(float x){
    float r; asm("v_rcp_f32 %0, %1" : "=v"(r) : "v"(x)); return r;
}
__device__ __forceinline__ float exp2_fast(float x){
    float r; asm("v_exp_f32 %0, %1" : "=v"(r) : "v"(x)); return r;
}
__device__ __forceinline__ float sigm(float x){
    return rcp_fast(1.0f + exp2_fast(x * -1.44269504f));
}
__device__ __forceinline__ float tanh_f(float x){
    return fmaf(-2.0f, rcp_fast(1.0f + exp2_fast(x * 2.88539008f)), 1.0f);
}
__device__ __forceinline__ hf8 ldw8(const float* src){
    float4 a = *(const float4*)src;
    float4 b = *(const float4*)(src + 4);
    hf8 r;
    r[0]=(f16)a.x; r[1]=(f16)a.y; r[2]=(f16)a.z; r[3]=(f16)a.w;
    r[4]=(f16)b.x; r[5]=(f16)b.y; r[6]=(f16)b.z; r[7]=(f16)b.w;
    return r;
}

// R17 = R16 roles (3 waves/SIMD) with GEMM state moved to LDS:
//  - x staged to xstage[16][68] f16 at t%16==14 (float2/thread, 2 transient regs)
//  - GEMM bias in biasP[512] LDS (permuted [tx][kg][r]), read per burst
//  - GEMM B-frags from xstage (2 x ds_read_b128 at burst)
// Waves 0-7: L1, 4 tiles x 4 h-kt + 4 GEMM x-tiles (burst t%16==15).
// Waves 8-11: L2, 4 tiles x 6 kt, setprio(1) cluster (T5).
// Gate-interleaved tiles (verified R5-R16): gate-row R = (rho&3)*H + 4*tau
// + (rho>>2); C/D row = kg*4+reg => lane (kg,rho) holds gates i,f,g,o of
// unit 4*tau+kg; lanes rho<4 select tile i=rho (2-level cndmask tree).
// xg[2][16][520] f16 dbuf holds Wih1*x+bias1, consumed per step as f16x4.

__launch_bounds__(NT, 3)
__global__ void lstm_mfma(const float* __restrict__ x,
                          const float* __restrict__ Wih1, const float* __restrict__ Whh1,
                          const float* __restrict__ bih1, const float* __restrict__ bhh1,
                          const float* __restrict__ Wih2, const float* __restrict__ Whh2,
                          const float* __restrict__ bih2, const float* __restrict__ bhh2,
                          const float* __restrict__ W1,   const float* __restrict__ b1,
                          const float* __restrict__ W2,   const float* __restrict__ b2,
                          float* __restrict__ out)
{
    __shared__ __align__(16) f16   xg[2][16][520];   // 33 KB
    __shared__ __align__(16) f16   xstage[16][68];   // 2.2 KB (pad 68)
    __shared__ __align__(16) float biasP[512];       // 2 KB  [tx][kg][r]
    __shared__ __align__(16) f16   h1buf[2][128];
    __shared__ __align__(16) f16   h2buf[2][64];
    __shared__ float headbuf[32];

    const int j    = threadIdx.x;      // 0..767
    const int b    = blockIdx.x;
    const int wave = j >> 6;           // 0..11
    const int lane = j & 63;
    const int rho  = lane & 15;
    const int kg   = lane >> 4;        // 0..3
    const bool l2w = (wave >= 8);
    const int  wv  = l2w ? (wave - 8) : wave;

    const float* xb = x + (size_t)b * TT * II;

    // ---------- prologue fills (before weight loads, loads in flight) ----------
    if (j < 512){
        // biasP: j = tx*16 + kg'*4 + r  ->  Rb = r*128 + 4*tx + kg'
        const int tx = j >> 4, kgp = (j >> 2) & 3, r = j & 3;
        const int Rb = r*128 + 4*tx + kgp;
        biasP[j] = bih1[Rb] + bhh1[Rb];
        // xstage: chunk 0 (steps 0..15): s = j>>5, c = (j&31)*2
        const int s = j >> 5, cc = (j & 31) * 2;
        float2 v = *(const float2*)(xb + s*II + cc);
        f16x2 w; w[0] = (f16)v.x; w[1] = (f16)v.y;
        *(f16x2*)&xstage[s][cc] = w;
    }

    // ---------- weights ----------
    hf8 A[24];                          // L1: A[i*4+kt] i<4 | L2: A[i*6+kt] i<4
    hf8 AX[8];                          // L1 only: 4 GEMM x-tiles
    float b2l0 = 0.f, b2l1 = 0.f, b2l2 = 0.f, b2l3 = 0.f;
    if (!l2w){
        #pragma unroll
        for (int i = 0; i < 4; ++i){
            const int tau = 4*wv + i;
            const int R   = (rho & 3)*128 + 4*tau + (rho >> 2);
            #pragma unroll
            for (int kt = 0; kt < 4; ++kt)
                A[i*4 + kt] = ldw8(Whh1 + R*128 + 32*kt + kg*8);
            AX[i*2 + 0] = ldw8(Wih1 + R*64 + kg*8);
            AX[i*2 + 1] = ldw8(Wih1 + R*64 + 32 + kg*8);
        }
    } else {
        #pragma unroll
        for (int i = 0; i < 4; ++i){
            const int tau2 = 4*wv + i;
            const int R    = (rho & 3)*64 + 4*tau2 + (rho >> 2);
            #pragma unroll
            for (int kt = 0; kt < 6; ++kt)
                A[i*6 + kt] = ldw8((kt < 4) ? (Wih2 + R*128 + 32*kt + kg*8)
                                            : (Whh2 + R*64  + 32*(kt-4) + kg*8));
        }
        const int u2 = 4*(4*wv + (rho & 3)) + kg;   // own unit (clamped dup)
        b2l0 = bih2[u2]       + bhh2[u2];
        b2l1 = bih2[64 + u2]  + bhh2[64 + u2];
        b2l2 = bih2[128 + u2] + bhh2[128 + u2];
        b2l3 = bih2[192 + u2] + bhh2[192 + u2];
    }

    if (j < 128) h1buf[0][j] = (f16)0.0f;
    if (j < 64)  h2buf[0][j] = (f16)0.0f;
    __syncthreads();

    // ---------- prologue GEMM: xg chunk 0 (L1 waves, from LDS) ----------
    if (!l2w){
        const f16* xs = &xstage[rho][0];
        hf8 xb0 = *(const hf8*)(xs + kg*8);
        hf8 xb1 = *(const hf8*)(xs + 32 + kg*8);
        #pragma unroll
        for (int i = 0; i < 4; ++i){
            ff4 bX = *(const ff4*)&biasP[(4*wv + i)*16 + kg*4];
            ff4 g = __builtin_amdgcn_mfma_f32_16x16x32_f16(AX[i*2+0], xb0, bX, 0, 0, 0);
            g     = __builtin_amdgcn_mfma_f32_16x16x32_f16(AX[i*2+1], xb1, g,  0, 0, 0);
            const int uX = 4*(4*wv + i) + kg;
            f16x4 w; w[0]=(f16)g[0]; w[1]=(f16)g[1]; w[2]=(f16)g[2]; w[3]=(f16)g[3];
            *(f16x4*)&xg[0][rho][uX*4] = w;
        }
    }
    __syncthreads();

    const ff4 zz = {0.0f, 0.0f, 0.0f, 0.0f};
    float c = 0.0f;
    int cur = 0;
    for (int t = 0; t < TT; ++t){
        const int trow = t & 15;
        const int cb   = (t >> 4) & 1;

        // stage next chunk's x at t%16==14 (threads 0..511; 2 transient regs)
        const bool ldx = (trow == 14) && (t + 2 < TT) && (j < 512);
        float2 sv;
        if (ldx){
            const int s = j >> 5, cc = (j & 31) * 2;
            sv = *(const float2*)(xb + (size_t)(t + 2 + s)*II + cc);
        }

        ff4 qd;
        if (!l2w){
            // xg consume (broadcast within dup lanes)
            const int myUm = 4*(4*wv + (rho & 3)) + kg;
            f16x4 xv = *(const f16x4*)&xg[cb][trow][myUm*4];

            const f16* h1c = h1buf[cur];
            hf8 bf0 = *(const hf8*)(h1c      + kg*8);
            hf8 bf1 = *(const hf8*)(h1c + 32 + kg*8);
            hf8 bf2 = *(const hf8*)(h1c + 64 + kg*8);
            hf8 bf3 = *(const hf8*)(h1c + 96 + kg*8);

            ff4 acc[4];
            #pragma unroll
            for (int i = 0; i < 4; ++i)
                acc[i] = __builtin_amdgcn_mfma_f32_16x16x32_f16(A[i*4+0], bf0, zz, 0, 0, 0);
            #pragma unroll
            for (int i = 0; i < 4; ++i)
                acc[i] = __builtin_amdgcn_mfma_f32_16x16x32_f16(A[i*4+1], bf1, acc[i], 0, 0, 0);
            #pragma unroll
            for (int i = 0; i < 4; ++i)
                acc[i] = __builtin_amdgcn_mfma_f32_16x16x32_f16(A[i*4+2], bf2, acc[i], 0, 0, 0);
            #pragma unroll
            for (int i = 0; i < 4; ++i)
                acc[i] = __builtin_amdgcn_mfma_f32_16x16x32_f16(A[i*4+3], bf3, acc[i], 0, 0, 0);

            ff4 s0 = (rho & 1) ? acc[1] : acc[0];
            ff4 s1 = (rho & 1) ? acc[3] : acc[2];
            qd     = (rho & 2) ? s1 : s0;

            // GEMM burst for next chunk (t%16==15), operands from LDS
            if (trow == 15 && t + 1 < TT){
                const f16* xs = &xstage[rho][0];
                hf8 xb0 = *(const hf8*)(xs + kg*8);
                hf8 xb1 = *(const hf8*)(xs + 32 + kg*8);
                #pragma unroll
                for (int i = 0; i < 4; ++i){
                    ff4 bX = *(const ff4*)&biasP[(4*wv + i)*16 + kg*4];
                    ff4 g = __builtin_amdgcn_mfma_f32_16x16x32_f16(AX[i*2+0], xb0, bX, 0, 0, 0);
                    g     = __builtin_amdgcn_mfma_f32_16x16x32_f16(AX[i*2+1], xb1, g,  0, 0, 0);
                    const int uX = 4*(4*wv + i) + kg;
                    f16x4 w; w[0]=(f16)g[0]; w[1]=(f16)g[1]; w[2]=(f16)g[2]; w[3]=(f16)g[3];
                    *(f16x4*)&xg[cb ^ 1][rho][uX*4] = w;
                }
            }

            // activation
            float ig = sigm(qd[0] + (float)xv[0]);
            float fg = sigm(qd[1] + (float)xv[1]);
            float gg = tanh_f(qd[2] + (float)xv[2]);
            float og = sigm(qd[3] + (float)xv[3]);
            c = fg*c + ig*gg;
            float hv = og * tanh_f(c);
            if (rho < 4) h1buf[cur ^ 1][4*(4*wv + rho) + kg] = (f16)hv;
        } else {
            const f16* h1c = h1buf[cur];
            const f16* h2c = h2buf[cur];
            hf8 bf0 = *(const hf8*)(h1c      + kg*8);
            hf8 bf1 = *(const hf8*)(h1c + 32 + kg*8);
            hf8 bf2 = *(const hf8*)(h1c + 64 + kg*8);
            hf8 bf3 = *(const hf8*)(h1c + 96 + kg*8);
            hf8 bf4 = *(const hf8*)(h2c      + kg*8);
            hf8 bf5 = *(const hf8*)(h2c + 32 + kg*8);
            ff4 acc[4];
            __builtin_amdgcn_s_setprio(1);     // T5: L2 staggers vs L1
            #pragma unroll
            for (int i = 0; i < 4; ++i)
                acc[i] = __builtin_amdgcn_mfma_f32_16x16x32_f16(A[i*6+0], bf0, zz, 0, 0, 0);
            #pragma unroll
            for (int kt = 1; kt < 6; ++kt){
                hf8 bb = (kt==1)?bf1:(kt==2)?bf2:(kt==3)?bf3:(kt==4)?bf4:bf5;
                #pragma unroll
                for (int i = 0; i < 4; ++i)
                    acc[i] = __builtin_amdgcn_mfma_f32_16x16x32_f16(A[i*6+kt], bb, acc[i], 0, 0, 0);
            }
            __builtin_amdgcn_s_setprio(0);
            ff4 s0 = (rho & 1) ? acc[1] : acc[0];
            ff4 s1 = (rho & 1) ? acc[3] : acc[2];
            qd     = (rho & 2) ? s1 : s0;

            float hv;
            if (t > 0){
                float ig = sigm(qd[0] + b2l0);
                float fg = sigm(qd[1] + b2l1);
                float gg = tanh_f(qd[2] + b2l2);
                float og = sigm(qd[3] + b2l3);
                c = fg*c + ig*gg;
                hv = og * tanh_f(c);
            } else {
                hv = 0.0f;                 // h2_{-1}=0, c2 untouched
            }
            if (rho < 4) h2buf[cur ^ 1][4*(4*wv + rho) + kg] = (f16)hv;
        }

        // publish staged x (vm-wait lands here, hidden under step compute)
        if (ldx){
            const int s = j >> 5, cc = (j & 31) * 2;
            f16x2 w; w[0] = (f16)sv.x; w[1] = (f16)sv.y;
            *(f16x2*)&xstage[s][cc] = w;
        }
        __syncthreads();
        cur ^= 1;
    }
    // after loop: cur==0; h1buf[0]=h1_{TT-1}, h2buf[0]=h2_{TT-2}

    // ---- epilogue: L2 step TT-1 (waves 8-11) ----
    if (l2w){
        const f16* h1c = h1buf[0];
        const f16* h2c = h2buf[0];
        hf8 bf0 = *(const hf8*)(h1c      + kg*8);
        hf8 bf1 = *(const hf8*)(h1c + 32 + kg*8);
        hf8 bf2 = *(const hf8*)(h1c + 64 + kg*8);
        hf8 bf3 = *(const hf8*)(h1c + 96 + kg*8);
        hf8 bf4 = *(const hf8*)(h2c      + kg*8);
        hf8 bf5 = *(const hf8*)(h2c + 32 + kg*8);
        ff4 acc[4];
        const ff4 zz2 = {0.0f, 0.0f, 0.0f, 0.0f};
        #pragma unroll
        for (int i = 0; i < 4; ++i)
            acc[i] = __builtin_amdgcn_mfma_f32_16x16x32_f16(A[i*6+0], bf0, zz2, 0, 0, 0);
        #pragma unroll
        for (int kt = 1; kt < 6; ++kt){
            hf8 bb = (kt==1)?bf1:(kt==2)?bf2:(kt==3)?bf3:(kt==4)?bf4:bf5;
            #pragma unroll
            for (int i = 0; i < 4; ++i)
                acc[i] = __builtin_amdgcn_mfma_f32_16x16x32_f16(A[i*6+kt], bb, acc[i], 0, 0, 0);
        }
        ff4 s0 = (rho & 1) ? acc[1] : acc[0];
        ff4 s1 = (rho & 1) ? acc[3] : acc[2];
        ff4 qd = (rho & 2) ? s1 : s0;
        float ig = sigm(qd[0] + b2l0);
        float fg = sigm(qd[1] + b2l1);
        float gg = tanh_f(qd[2] + b2l2);
        float og = sigm(qd[3] + b2l3);
        c = fg*c + ig*gg;
        float hv = og * tanh_f(c);
        if (rho < 4) h2buf[1][4*(4*wv + rho) + kg] = (f16)hv;
    }
    __syncthreads();

    // ---- MLP head (final h2 in h2buf[1]) ----
    if (j < 32){
        float a = b1[j];
        const float* w = W1 + j*64;
        #pragma unroll
        for (int k = 0; k < 64; ++k) a = fmaf(w[k], (float)h2buf[1][k], a);
        headbuf[j] = sigm(a);
    }
    __syncthreads();
    if (j == 0){
        float a = b2[0];
        #pragma unroll
        for (int k = 0; k < 32; ++k) a = fmaf(W2[k], headbuf[k], a);
        out[b] = sigm(a);
    }
}

extern "C" void kernel_launch(void* const* d_in, const int* in_sizes, int n_in,
                              void* d_out, int out_size, void* d_ws, size_t ws_size,
                              hipStream_t stream)
{
    (void)in_sizes; (void)n_in; (void)d_ws; (void)ws_size; (void)out_size;
    lstm_mfma<<<NB, NT, 0, stream>>>(
        (const float*)d_in[0],
        (const float*)d_in[1], (const float*)d_in[2],
        (const float*)d_in[3], (const float*)d_in[4],
        (const float*)d_in[5], (const float*)d_in[6],
        (const float*)d_in[7], (const float*)d_in[8],
        (const float*)d_in[9], (const float*)d_in[10],
        (const float*)d_in[11], (const float*)d_in[12],
        (float*)d_out);
}